// Round 1
// baseline (158.534 us; speedup 1.0000x reference)
//
#include <hip/hip_runtime.h>
#include <hip/hip_bf16.h>
#include <stdint.h>
#include <stddef.h>

// ContrastiveLoss: N=4096, D=768.
// loss = mean_{ij} (1-g)*d2 + g*max(2-sqrt(d2),0)^2,
// d2 = sa[i]+sb[j]-2*dot(i,j)+2e-6*(ra[i]-rb[j])+768e-12 (clamped at 0).
// R6: fp8 e4m3 GEMM, k-permuted global layout, XOR-8 LDS (R2's proven
//     conflict-free frag reads), de-duplicated epilogue. 135.5 us.
// R7 (this): gt (67 MB, was 2/3 of prologue traffic) is no longer read+packed
//     in the prologue. The GEMM is compute-bound with HBM idle (operands are
//     6.3 MB L2/L3-resident fp8), so each block now reads its own 64 KB gt
//     tile during K-iterations 0..3 (int4 loads issued BEFORE the barrier ->
//     latency hidden under staging+MFMA), ballot-packs into a 2 KB LDS
//     bitmask gmask[128][4] (word j bit c = col 4c+j). Prologue = cast only
//     (31.5 MB). Epilogue reads gmask instead of global gtp.
// Lesson log: R4 32x32 frags = structural 4-way conflict; R3 dbuf = spill;
//     WRITE_SIZE is the spill detector; only R2's LDS algebra measures 0.

#define NROWS 4096
#define DIM   768
#define BM    128
#define BN    128
#define BKE   128              // K elements per tile (128 B fp8 rows)
#define MARGIN 2.0f
#define EPSV   1e-6f

typedef float f32x4 __attribute__((ext_vector_type(4)));
typedef long  lng2  __attribute__((ext_vector_type(2)));
typedef unsigned long long u64;
typedef unsigned char fp8_t;

// Permutation of each 128-elem k-segment, baked into the fp8 global layout:
// element (kk,q,j) [kk=K32-window 0..3, q=quad 0..3, j=0..7] is stored at
// byte ((kk>>1)*4 + q)*16 + (kk&1)*8 + j. Both A and B use it => dot
// products are unchanged (same k-order on both operands).

// ---------------- prologue: fp8 cast + exact fp32 row sums (2048 blocks) ---
__global__ __launch_bounds__(256) void prologue_kernel(
    const float* __restrict__ A, const float* __restrict__ B,
    fp8_t* __restrict__ Af8, fp8_t* __restrict__ Bf8,
    float* __restrict__ sa, float* __restrict__ sb,
    float* __restrict__ ra, float* __restrict__ rb,
    float* __restrict__ out)
{
    const int tid  = threadIdx.x;
    const int wave = tid >> 6;
    const int lane = tid & 63;
    const int bx   = blockIdx.x;

    if (bx == 0 && tid == 0) out[0] = 0.0f;

    const int isB  = bx >= 1024;
    const int row  = (bx & 1023) * 4 + wave;
    const float* X = isB ? B : A;
    fp8_t* Xb      = isB ? Bf8 : Af8;
    float* sdst    = isB ? sb : sa;
    float* rdst    = isB ? rb : ra;

    const float4* xr = (const float4*)(X + (size_t)row * DIM);
    unsigned int* xb = (unsigned int*)(Xb + (size_t)row * DIM);

    float sum = 0.0f, sq = 0.0f;
    #pragma unroll
    for (int jb = 0; jb < 3; ++jb) {
        float4 v = xr[lane + 64 * jb];
        int pk = 0;
        pk = __builtin_amdgcn_cvt_pk_fp8_f32(v.x, v.y, pk, false);
        pk = __builtin_amdgcn_cvt_pk_fp8_f32(v.z, v.w, pk, true);
        // permuted destination dword
        const int e4  = lane + 64 * jb;     // source dword idx in row
        const int seg = e4 >> 5;            // 128-elem segment
        const int e   = (e4 & 31) * 4;      // elem within segment
        const int kk  = e >> 5;
        const int q   = (e >> 3) & 3;
        const int jj  = e & 7;              // 0 or 4
        const int pos = ((kk >> 1) * 4 + q) * 16 + (kk & 1) * 8 + jj;
        xb[seg * 32 + (pos >> 2)] = (unsigned int)pk;
        sum += (v.x + v.y) + (v.z + v.w);
        sq  += v.x * v.x + v.y * v.y + v.z * v.z + v.w * v.w;
    }
    #pragma unroll
    for (int off = 32; off > 0; off >>= 1) {
        sum += __shfl_down(sum, off);
        sq  += __shfl_down(sq,  off);
    }
    if (lane == 0) { rdst[row] = sum; sdst[row] = sq; }
}

// ---------------- fused GEMM + loss (fp8 e4m3, k-permuted layout) ----------
// 128x128 tile / 256 threads (4 waves x 64x64 of 4x4 16x16x32 fp8 MFMA).
// BKE=128 (128-B LDS rows), single-buffered 32 KB LDS, 2-barrier K-loop.
// Frag reads: b128 at chunk c = kk2*4 + q, slot (c ^ (row&7)) — R2's
// measured-conflict-free algebra. gt tile (64 KB) read during kb=0..3 and
// ballot-packed into gmask: gmask[r][j] bit c = (gt[m0+r][n0+4c+j] != 0).
__global__ __launch_bounds__(256, 4) void loss_kernel(
    const fp8_t* __restrict__ A, const fp8_t* __restrict__ B,
    const float* __restrict__ sa, const float* __restrict__ sb,
    const float* __restrict__ ra, const float* __restrict__ rb,
    const int* __restrict__ gt, float* __restrict__ out)
{
    __shared__ __align__(16) fp8_t As[BM * BKE];  // 16 KB
    __shared__ __align__(16) fp8_t Bs[BN * BKE];  // 16 KB
    __shared__ unsigned int gmask[BM][4];         // 2 KB bitmask

    const int tid  = threadIdx.x;
    const int wave = tid >> 6;
    const int lane = tid & 63;
    const int m0 = blockIdx.y * BM;
    const int n0 = blockIdx.x * BN;

    f32x4 acc[4][4] = {};

    const int fr = lane & 15;            // frag row (A) / frag col (B)
    const int q  = lane >> 4;            // quad
    const int wm = (wave >> 1) * 64;
    const int wn = (wave & 1) * 64;

    // staging: chunk c (16 B) -> row c>>3, slot c&7; LDS slot p of row holds
    // global chunk p ^ (row&7)   [XOR-8 swizzle]
    const int srow = lane >> 3;
    const int sp   = lane & 7;

    for (int kb = 0; kb < DIM / BKE; ++kb) {
        const int k0 = kb * BKE;
        const int rbase = kb * 32 + wave * 8;

        // gt tile loads for this block: issue BEFORE the barrier (VGPR-only,
        // no LDS hazard) so the ballots below wait only on these (vmcnt(8)),
        // never draining the staging queue.
        int4 gv[4];
        if (kb < 4) {
            #pragma unroll
            for (int t = 0; t < 4; ++t) {
                const int rloc = rbase + t * 2 + (lane >> 5);
                gv[t] = *((const int4*)(gt + (size_t)(m0 + rloc) * NROWS + n0)
                          + (lane & 31));
            }
        }

        __syncthreads();   // prev iter's LDS reads done
        #pragma unroll
        for (int j = 0; j < 4; ++j) {          // A: 1024 chunks, 256/wave
            const int c0  = wave * 256 + j * 64;            // wave-uniform
            const int row = (c0 >> 3) + srow;
            const int gcx = sp ^ (row & 7);
            const fp8_t* ga = A + (size_t)(m0 + row) * DIM + k0 + gcx * 16;
            __builtin_amdgcn_global_load_lds(
                (const __attribute__((address_space(1))) void*)ga,
                (__attribute__((address_space(3))) void*)(As + c0 * 16),
                16, 0, 0);
        }
        #pragma unroll
        for (int j = 0; j < 4; ++j) {          // B: 1024 chunks, 256/wave
            const int c0  = wave * 256 + j * 64;
            const int row = (c0 >> 3) + srow;
            const int gcx = sp ^ (row & 7);
            const fp8_t* gb = B + (size_t)(n0 + row) * DIM + k0 + gcx * 16;
            __builtin_amdgcn_global_load_lds(
                (const __attribute__((address_space(1))) void*)gb,
                (__attribute__((address_space(3))) void*)(Bs + c0 * 16),
                16, 0, 0);
        }

        // ballot-pack gt tile rows rbase..rbase+7 into gmask (lanes 0..31 =
        // even row, 32..63 = odd row; bit l of ballot = int4 slot l&31).
        if (kb < 4) {
            #pragma unroll
            for (int t = 0; t < 4; ++t) {
                const int rloc = rbase + t * 2 + (lane >> 5);
                #pragma unroll
                for (int j = 0; j < 4; ++j) {
                    const int vj = (j == 0) ? gv[t].x : (j == 1) ? gv[t].y
                                 : (j == 2) ? gv[t].z : gv[t].w;
                    const u64 b = __ballot(vj != 0);
                    if ((lane & 31) == 0)
                        gmask[rloc][j] = (unsigned int)(b >> lane);
                }
            }
        }
        __syncthreads();   // staging complete

        #pragma unroll
        for (int kk2 = 0; kk2 < 2; ++kk2) {    // each step: 2 K=32 windows
            const int c = kk2 * 4 + q;         // consecutive chunk per quad
            lng2 ap[4], bp[4];
            #pragma unroll
            for (int i = 0; i < 4; ++i) {
                const int ar = wm + i * 16 + fr;
                const int br = wn + i * 16 + fr;
                ap[i] = *(const lng2*)(As + ar * BKE + ((c ^ (ar & 7)) * 16));
                bp[i] = *(const lng2*)(Bs + br * BKE + ((c ^ (br & 7)) * 16));
            }
            #pragma unroll
            for (int mi = 0; mi < 4; ++mi)
                #pragma unroll
                for (int ni = 0; ni < 4; ++ni)
                    acc[mi][ni] = __builtin_amdgcn_mfma_f32_16x16x32_fp8_fp8(
                        ap[mi][0], bp[ni][0], acc[mi][ni], 0, 0, 0);
            #pragma unroll
            for (int mi = 0; mi < 4; ++mi)
                #pragma unroll
                for (int ni = 0; ni < 4; ++ni)
                    acc[mi][ni] = __builtin_amdgcn_mfma_f32_16x16x32_fp8_fp8(
                        ap[mi][1], bp[ni][1], acc[mi][ni], 0, 0, 0);
        }
    }

    // ---- fused epilogue: C/D col=lane&15, row=(lane>>4)*4+reg ----
    // Single traversal; per-element exact correction branch (never taken for
    // this data: min d2 ~ 1250 >> 4) — no dup loop, no spill trigger.
    // gt bit for col = n0+wn+ni*16+cq: word j=cq&3, bit (wn+ni*16+cq)>>2.
    const int cq = lane & 15;
    const int rq = (lane >> 4) * 4;
    const int jm = cq & 3;

    float cc[4];
    #pragma unroll
    for (int ni = 0; ni < 4; ++ni) {
        const int col = n0 + wn + ni * 16 + cq;
        cc[ni] = sb[col] - 2.0f * EPSV * rb[col];
    }

    float local = 0.0f;
    #pragma unroll
    for (int mi = 0; mi < 4; ++mi) {
        #pragma unroll
        for (int rr = 0; rr < 4; ++rr) {
            const int rloc = wm + mi * 16 + rq + rr;
            const int row  = m0 + rloc;
            const float crr = sa[row] + 2.0f * EPSV * ra[row]
                            + (float)DIM * EPSV * EPSV;
            const unsigned int gw = gmask[rloc][jm];
            #pragma unroll
            for (int ni = 0; ni < 4; ++ni) {
                const float d2 = (crr + cc[ni]) - 2.0f * acc[mi][ni][rr];
                const float gf =
                    (float)((gw >> ((wn + ni * 16 + cq) >> 2)) & 1u);
                float contrib = d2 - gf * d2;           // hinge==0 fast path
                if (__builtin_expect(d2 < 4.0f, 0)) {   // exact, never taken
                    const float d2c  = fmaxf(d2, 0.0f);
                    const float dist = sqrtf(d2c);
                    const float h    = fmaxf(MARGIN - dist, 0.0f);
                    contrib = (1.0f - gf) * d2c + gf * h * h;
                }
                local += contrib;
            }
        }
    }

    #pragma unroll
    for (int off = 32; off > 0; off >>= 1) local += __shfl_down(local, off);

    float* redp = (float*)As;   // reuse LDS for block reduction
    __syncthreads();
    if (lane == 0) redp[wave] = local;
    __syncthreads();
    if (tid == 0) {
        const float s = (redp[0] + redp[1]) + (redp[2] + redp[3]);
        atomicAdd(out, s * (1.0f / (4096.0f * 4096.0f)));
    }
}

// ---------------------------------------------------------------------------
extern "C" void kernel_launch(void* const* d_in, const int* in_sizes, int n_in,
                              void* d_out, int out_size, void* d_ws, size_t ws_size,
                              hipStream_t stream)
{
    const float* A  = (const float*)d_in[0];
    const float* B  = (const float*)d_in[1];
    const int*   gt = (const int*)d_in[2];
    float* out = (float*)d_out;

    char* ws = (char*)d_ws;
    const size_t NB8 = (size_t)NROWS * DIM;   // 3,145,728 B per fp8 matrix
    fp8_t* Af8 = (fp8_t*)(ws);
    fp8_t* Bf8 = (fp8_t*)(ws + NB8);
    float* sa = (float*)(ws + 2 * NB8);
    float* sb = (float*)(ws + 2 * NB8 + 16384);
    float* ra = (float*)(ws + 2 * NB8 + 32768);
    float* rb = (float*)(ws + 2 * NB8 + 49152);

    prologue_kernel<<<dim3(2048), 256, 0, stream>>>(
        A, B, Af8, Bf8, sa, sb, ra, rb, out);
    loss_kernel<<<dim3(NROWS / BN, NROWS / BM), 256, 0, stream>>>(
        Af8, Bf8, sa, sb, ra, rb, gt, out);
}

// Round 2
// 154.946 us; speedup vs baseline: 1.0232x; 1.0232x over previous
//
#include <hip/hip_runtime.h>
#include <hip/hip_bf16.h>
#include <stdint.h>
#include <stddef.h>

// ContrastiveLoss: N=4096, D=768.
// loss = mean_{ij} (1-g)*d2 + g*max(2-sqrt(d2),0)^2,
// d2 = sa[i]+sb[j]-2*dot(i,j)+2e-6*(ra[i]-rb[j])+768e-12 (clamped at 0).
// R6: fp8 e4m3 GEMM, k-permuted global layout, XOR-8 LDS (R2's proven
//     conflict-free frag reads), de-duplicated epilogue. 135.5 us.
// R7 (FAILED, 158.5): gt tile read inside K-loop, but ballots placed BEFORE
//     the staging barrier -> every wave stalls ~900cyc on cold gt before
//     sync2 gates the MFMA; rolled loop (runtime kb<4) degraded scheduling.
//     MfmaUtil 13%, loss 74.5 us.
// R8 (this): same gt-in-GEMM traffic plan (loss FETCH ~80 MB, prologue cast-
//     only 31.5 MB ~7 us), but gt loads issue at iteration TOP (before
//     sync1) and ballots run AFTER the MFMA block (end of iteration) where
//     vmcnt is already drained -> gt latency hides under staging+32 MFMAs.
//     K-loop fully unrolled so kb<4 is compile-time (R6's straight-line
//     body restored). gv = 16 transient VGPRs/iter, disjoint when unrolled.
// Lesson log: R4 32x32 frags = structural 4-way conflict; R3 dbuf = spill;
//     WRITE_SIZE is the spill detector; only R2's LDS algebra measures 0;
//     R7: never put an HBM-latency wait between staging and its barrier.

#define NROWS 4096
#define DIM   768
#define BM    128
#define BN    128
#define BKE   128              // K elements per tile (128 B fp8 rows)
#define MARGIN 2.0f
#define EPSV   1e-6f

typedef float f32x4 __attribute__((ext_vector_type(4)));
typedef long  lng2  __attribute__((ext_vector_type(2)));
typedef unsigned long long u64;
typedef unsigned char fp8_t;

// Permutation of each 128-elem k-segment, baked into the fp8 global layout:
// element (kk,q,j) [kk=K32-window 0..3, q=quad 0..3, j=0..7] is stored at
// byte ((kk>>1)*4 + q)*16 + (kk&1)*8 + j. Both A and B use it => dot
// products are unchanged (same k-order on both operands).

// ---------------- prologue: fp8 cast + exact fp32 row sums (2048 blocks) ---
__global__ __launch_bounds__(256) void prologue_kernel(
    const float* __restrict__ A, const float* __restrict__ B,
    fp8_t* __restrict__ Af8, fp8_t* __restrict__ Bf8,
    float* __restrict__ sa, float* __restrict__ sb,
    float* __restrict__ ra, float* __restrict__ rb,
    float* __restrict__ out)
{
    const int tid  = threadIdx.x;
    const int wave = tid >> 6;
    const int lane = tid & 63;
    const int bx   = blockIdx.x;

    if (bx == 0 && tid == 0) out[0] = 0.0f;

    const int isB  = bx >= 1024;
    const int row  = (bx & 1023) * 4 + wave;
    const float* X = isB ? B : A;
    fp8_t* Xb      = isB ? Bf8 : Af8;
    float* sdst    = isB ? sb : sa;
    float* rdst    = isB ? rb : ra;

    const float4* xr = (const float4*)(X + (size_t)row * DIM);
    unsigned int* xb = (unsigned int*)(Xb + (size_t)row * DIM);

    float sum = 0.0f, sq = 0.0f;
    #pragma unroll
    for (int jb = 0; jb < 3; ++jb) {
        float4 v = xr[lane + 64 * jb];
        int pk = 0;
        pk = __builtin_amdgcn_cvt_pk_fp8_f32(v.x, v.y, pk, false);
        pk = __builtin_amdgcn_cvt_pk_fp8_f32(v.z, v.w, pk, true);
        // permuted destination dword
        const int e4  = lane + 64 * jb;     // source dword idx in row
        const int seg = e4 >> 5;            // 128-elem segment
        const int e   = (e4 & 31) * 4;      // elem within segment
        const int kk  = e >> 5;
        const int q   = (e >> 3) & 3;
        const int jj  = e & 7;              // 0 or 4
        const int pos = ((kk >> 1) * 4 + q) * 16 + (kk & 1) * 8 + jj;
        xb[seg * 32 + (pos >> 2)] = (unsigned int)pk;
        sum += (v.x + v.y) + (v.z + v.w);
        sq  += v.x * v.x + v.y * v.y + v.z * v.z + v.w * v.w;
    }
    #pragma unroll
    for (int off = 32; off > 0; off >>= 1) {
        sum += __shfl_down(sum, off);
        sq  += __shfl_down(sq,  off);
    }
    if (lane == 0) { rdst[row] = sum; sdst[row] = sq; }
}

// ---------------- fused GEMM + loss (fp8 e4m3, k-permuted layout) ----------
// 128x128 tile / 256 threads (4 waves x 64x64 of 4x4 16x16x32 fp8 MFMA).
// BKE=128 (128-B LDS rows), single-buffered 32 KB LDS, 2-barrier K-loop.
// Frag reads: b128 at chunk c = kk2*4 + q, slot (c ^ (row&7)) — R2's
// measured-conflict-free algebra. gt tile (64 KB) read during kb=0..3
// (loads at iteration top, ballots after MFMA) into gmask:
// gmask[r][j] bit c = (gt[m0+r][n0+4c+j] != 0).
__global__ __launch_bounds__(256, 4) void loss_kernel(
    const fp8_t* __restrict__ A, const fp8_t* __restrict__ B,
    const float* __restrict__ sa, const float* __restrict__ sb,
    const float* __restrict__ ra, const float* __restrict__ rb,
    const int* __restrict__ gt, float* __restrict__ out)
{
    __shared__ __align__(16) fp8_t As[BM * BKE];  // 16 KB
    __shared__ __align__(16) fp8_t Bs[BN * BKE];  // 16 KB
    __shared__ unsigned int gmask[BM][4];         // 2 KB bitmask

    const int tid  = threadIdx.x;
    const int wave = tid >> 6;
    const int lane = tid & 63;
    const int m0 = blockIdx.y * BM;
    const int n0 = blockIdx.x * BN;

    f32x4 acc[4][4] = {};

    const int fr = lane & 15;            // frag row (A) / frag col (B)
    const int q  = lane >> 4;            // quad
    const int wm = (wave >> 1) * 64;
    const int wn = (wave & 1) * 64;

    // staging: chunk c (16 B) -> row c>>3, slot c&7; LDS slot p of row holds
    // global chunk p ^ (row&7)   [XOR-8 swizzle]
    const int srow = lane >> 3;
    const int sp   = lane & 7;

    #pragma unroll
    for (int kb = 0; kb < DIM / BKE; ++kb) {
        const int k0 = kb * BKE;
        const int rbase = kb * 32 + wave * 8;

        // gt tile loads for this block: issued at iteration TOP (VGPR-only,
        // no LDS hazard). Consumed only after the MFMA block below -> HBM
        // latency hides under sync1 + staging + sync2 + 32 MFMAs.
        int4 gv[4];
        if (kb < 4) {
            #pragma unroll
            for (int t = 0; t < 4; ++t) {
                const int rloc = rbase + t * 2 + (lane >> 5);
                gv[t] = *((const int4*)(gt + (size_t)(m0 + rloc) * NROWS + n0)
                          + (lane & 31));
            }
        }

        __syncthreads();   // prev iter's LDS reads done
        #pragma unroll
        for (int j = 0; j < 4; ++j) {          // A: 1024 chunks, 256/wave
            const int c0  = wave * 256 + j * 64;            // wave-uniform
            const int row = (c0 >> 3) + srow;
            const int gcx = sp ^ (row & 7);
            const fp8_t* ga = A + (size_t)(m0 + row) * DIM + k0 + gcx * 16;
            __builtin_amdgcn_global_load_lds(
                (const __attribute__((address_space(1))) void*)ga,
                (__attribute__((address_space(3))) void*)(As + c0 * 16),
                16, 0, 0);
        }
        #pragma unroll
        for (int j = 0; j < 4; ++j) {          // B: 1024 chunks, 256/wave
            const int c0  = wave * 256 + j * 64;
            const int row = (c0 >> 3) + srow;
            const int gcx = sp ^ (row & 7);
            const fp8_t* gb = B + (size_t)(n0 + row) * DIM + k0 + gcx * 16;
            __builtin_amdgcn_global_load_lds(
                (const __attribute__((address_space(1))) void*)gb,
                (__attribute__((address_space(3))) void*)(Bs + c0 * 16),
                16, 0, 0);
        }
        __syncthreads();   // staging complete

        #pragma unroll
        for (int kk2 = 0; kk2 < 2; ++kk2) {    // each step: 2 K=32 windows
            const int c = kk2 * 4 + q;         // consecutive chunk per quad
            lng2 ap[4], bp[4];
            #pragma unroll
            for (int i = 0; i < 4; ++i) {
                const int ar = wm + i * 16 + fr;
                const int br = wn + i * 16 + fr;
                ap[i] = *(const lng2*)(As + ar * BKE + ((c ^ (ar & 7)) * 16));
                bp[i] = *(const lng2*)(Bs + br * BKE + ((c ^ (br & 7)) * 16));
            }
            #pragma unroll
            for (int mi = 0; mi < 4; ++mi)
                #pragma unroll
                for (int ni = 0; ni < 4; ++ni)
                    acc[mi][ni] = __builtin_amdgcn_mfma_f32_16x16x32_fp8_fp8(
                        ap[mi][0], bp[ni][0], acc[mi][ni], 0, 0, 0);
            #pragma unroll
            for (int mi = 0; mi < 4; ++mi)
                #pragma unroll
                for (int ni = 0; ni < 4; ++ni)
                    acc[mi][ni] = __builtin_amdgcn_mfma_f32_16x16x32_fp8_fp8(
                        ap[mi][1], bp[ni][1], acc[mi][ni], 0, 0, 0);
        }

        // ballot-pack gt tile rows rbase..rbase+7 into gmask AFTER the MFMA
        // block: vmcnt already drained at sync2, so this waits on nothing.
        // (lanes 0..31 = even row, 32..63 = odd row; ballot bit l = slot
        // l&31.) gmask writes ordered before epilogue reads by kb=4's sync1.
        if (kb < 4) {
            #pragma unroll
            for (int t = 0; t < 4; ++t) {
                const int rloc = rbase + t * 2 + (lane >> 5);
                #pragma unroll
                for (int j = 0; j < 4; ++j) {
                    const int vj = (j == 0) ? gv[t].x : (j == 1) ? gv[t].y
                                 : (j == 2) ? gv[t].z : gv[t].w;
                    const u64 b = __ballot(vj != 0);
                    if ((lane & 31) == 0)
                        gmask[rloc][j] = (unsigned int)(b >> lane);
                }
            }
        }
    }

    // ---- fused epilogue: C/D col=lane&15, row=(lane>>4)*4+reg ----
    // Single traversal; per-element exact correction branch (never taken for
    // this data: min d2 ~ 1250 >> 4) — no dup loop, no spill trigger.
    // gt bit for col = n0+wn+ni*16+cq: word j=cq&3, bit (wn+ni*16+cq)>>2.
    const int cq = lane & 15;
    const int rq = (lane >> 4) * 4;
    const int jm = cq & 3;

    float cc[4];
    #pragma unroll
    for (int ni = 0; ni < 4; ++ni) {
        const int col = n0 + wn + ni * 16 + cq;
        cc[ni] = sb[col] - 2.0f * EPSV * rb[col];
    }

    float local = 0.0f;
    #pragma unroll
    for (int mi = 0; mi < 4; ++mi) {
        #pragma unroll
        for (int rr = 0; rr < 4; ++rr) {
            const int rloc = wm + mi * 16 + rq + rr;
            const int row  = m0 + rloc;
            const float crr = sa[row] + 2.0f * EPSV * ra[row]
                            + (float)DIM * EPSV * EPSV;
            const unsigned int gw = gmask[rloc][jm];
            #pragma unroll
            for (int ni = 0; ni < 4; ++ni) {
                const float d2 = (crr + cc[ni]) - 2.0f * acc[mi][ni][rr];
                const float gf =
                    (float)((gw >> ((wn + ni * 16 + cq) >> 2)) & 1u);
                float contrib = d2 - gf * d2;           // hinge==0 fast path
                if (__builtin_expect(d2 < 4.0f, 0)) {   // exact, never taken
                    const float d2c  = fmaxf(d2, 0.0f);
                    const float dist = sqrtf(d2c);
                    const float h    = fmaxf(MARGIN - dist, 0.0f);
                    contrib = (1.0f - gf) * d2c + gf * h * h;
                }
                local += contrib;
            }
        }
    }

    #pragma unroll
    for (int off = 32; off > 0; off >>= 1) local += __shfl_down(local, off);

    float* redp = (float*)As;   // reuse LDS for block reduction
    __syncthreads();
    if (lane == 0) redp[wave] = local;
    __syncthreads();
    if (tid == 0) {
        const float s = (redp[0] + redp[1]) + (redp[2] + redp[3]);
        atomicAdd(out, s * (1.0f / (4096.0f * 4096.0f)));
    }
}

// ---------------------------------------------------------------------------
extern "C" void kernel_launch(void* const* d_in, const int* in_sizes, int n_in,
                              void* d_out, int out_size, void* d_ws, size_t ws_size,
                              hipStream_t stream)
{
    const float* A  = (const float*)d_in[0];
    const float* B  = (const float*)d_in[1];
    const int*   gt = (const int*)d_in[2];
    float* out = (float*)d_out;

    char* ws = (char*)d_ws;
    const size_t NB8 = (size_t)NROWS * DIM;   // 3,145,728 B per fp8 matrix
    fp8_t* Af8 = (fp8_t*)(ws);
    fp8_t* Bf8 = (fp8_t*)(ws + NB8);
    float* sa = (float*)(ws + 2 * NB8);
    float* sb = (float*)(ws + 2 * NB8 + 16384);
    float* ra = (float*)(ws + 2 * NB8 + 32768);
    float* rb = (float*)(ws + 2 * NB8 + 49152);

    prologue_kernel<<<dim3(2048), 256, 0, stream>>>(
        A, B, Af8, Bf8, sa, sb, ra, rb, out);
    loss_kernel<<<dim3(NROWS / BN, NROWS / BM), 256, 0, stream>>>(
        Af8, Bf8, sa, sb, ra, rb, gt, out);
}

// Round 3
// 138.078 us; speedup vs baseline: 1.1481x; 1.1222x over previous
//
#include <hip/hip_runtime.h>
#include <hip/hip_bf16.h>
#include <stdint.h>
#include <stddef.h>

// ContrastiveLoss: N=4096, D=768.
// loss = mean_{ij} (1-g)*d2 + g*max(2-sqrt(d2),0)^2,
// d2 = sa[i]+sb[j]-2*dot(i,j)+2e-6*(ra[i]-rb[j])+768e-12 (clamped at 0).
// R6: fp8 e4m3 GEMM, k-permuted global layout, XOR-8 LDS (R2's proven
//     conflict-free frag reads), de-duplicated epilogue. 135.5 us.
// R7 (FAILED, 158.5): gt packed inside K-loop before staging barrier ->
//     cold-HBM latency serialized ahead of MFMA. MfmaUtil 13%.
// R8 (FAILED, 154.9): gt loads at iteration top, ballots after MFMA. Still
//     slow (loss 58 us): __syncthreads() = s_waitcnt vmcnt(0)+s_barrier
//     drains the in-flight gt loads at EVERY staging barrier -> ~900cyc
//     added to 4 of 6 K-iterations. gt must not touch the K-loop at all.
// R9 (this): K-loop byte-identical to R6 (pure GEMM, proven ~33 us/780 TF,
//     0 conflicts). gt read DIRECTLY in the epilogue (64 scalar int loads
//     per thread, gf=(v!=0)), after the last barrier where the scheduler
//     hoists them over the final MFMAs. No prologue packing (cast-only
//     prologue, 31.5 MB, ~7 us), no gmask, no ballots. Per-wave read
//     pattern tiles aligned 256B segments, each byte read exactly once ->
//     no fetch amplification.
// Lesson log: R4 32x32 frags = structural 4-way conflict; R3 dbuf = spill;
//     WRITE_SIZE is the spill detector; only R2's LDS algebra measures 0;
//     R7/R8: any vmem in flight across __syncthreads gets drained -> never
//     overlap cold loads with a barriered K-loop in plain HIP.

#define NROWS 4096
#define DIM   768
#define BM    128
#define BN    128
#define BKE   128              // K elements per tile (128 B fp8 rows)
#define MARGIN 2.0f
#define EPSV   1e-6f

typedef float f32x4 __attribute__((ext_vector_type(4)));
typedef long  lng2  __attribute__((ext_vector_type(2)));
typedef unsigned long long u64;
typedef unsigned char fp8_t;

// Permutation of each 128-elem k-segment, baked into the fp8 global layout:
// element (kk,q,j) [kk=K32-window 0..3, q=quad 0..3, j=0..7] is stored at
// byte ((kk>>1)*4 + q)*16 + (kk&1)*8 + j. Both A and B use it => dot
// products are unchanged (same k-order on both operands).

// ---------------- prologue: fp8 cast + exact fp32 row sums (2048 blocks) ---
__global__ __launch_bounds__(256) void prologue_kernel(
    const float* __restrict__ A, const float* __restrict__ B,
    fp8_t* __restrict__ Af8, fp8_t* __restrict__ Bf8,
    float* __restrict__ sa, float* __restrict__ sb,
    float* __restrict__ ra, float* __restrict__ rb,
    float* __restrict__ out)
{
    const int tid  = threadIdx.x;
    const int wave = tid >> 6;
    const int lane = tid & 63;
    const int bx   = blockIdx.x;

    if (bx == 0 && tid == 0) out[0] = 0.0f;

    const int isB  = bx >= 1024;
    const int row  = (bx & 1023) * 4 + wave;
    const float* X = isB ? B : A;
    fp8_t* Xb      = isB ? Bf8 : Af8;
    float* sdst    = isB ? sb : sa;
    float* rdst    = isB ? rb : ra;

    const float4* xr = (const float4*)(X + (size_t)row * DIM);
    unsigned int* xb = (unsigned int*)(Xb + (size_t)row * DIM);

    float sum = 0.0f, sq = 0.0f;
    #pragma unroll
    for (int jb = 0; jb < 3; ++jb) {
        float4 v = xr[lane + 64 * jb];
        int pk = 0;
        pk = __builtin_amdgcn_cvt_pk_fp8_f32(v.x, v.y, pk, false);
        pk = __builtin_amdgcn_cvt_pk_fp8_f32(v.z, v.w, pk, true);
        // permuted destination dword
        const int e4  = lane + 64 * jb;     // source dword idx in row
        const int seg = e4 >> 5;            // 128-elem segment
        const int e   = (e4 & 31) * 4;      // elem within segment
        const int kk  = e >> 5;
        const int q   = (e >> 3) & 3;
        const int jj  = e & 7;              // 0 or 4
        const int pos = ((kk >> 1) * 4 + q) * 16 + (kk & 1) * 8 + jj;
        xb[seg * 32 + (pos >> 2)] = (unsigned int)pk;
        sum += (v.x + v.y) + (v.z + v.w);
        sq  += v.x * v.x + v.y * v.y + v.z * v.z + v.w * v.w;
    }
    #pragma unroll
    for (int off = 32; off > 0; off >>= 1) {
        sum += __shfl_down(sum, off);
        sq  += __shfl_down(sq,  off);
    }
    if (lane == 0) { rdst[row] = sum; sdst[row] = sq; }
}

// ---------------- fused GEMM + loss (fp8 e4m3, k-permuted layout) ----------
// 128x128 tile / 256 threads (4 waves x 64x64 of 4x4 16x16x32 fp8 MFMA).
// BKE=128 (128-B LDS rows), single-buffered 32 KB LDS, 2-barrier K-loop.
// Frag reads: b128 at chunk c = kk2*4 + q, slot (c ^ (row&7)) — R2's
// measured-conflict-free algebra. gt is read directly in the epilogue.
__global__ __launch_bounds__(256, 4) void loss_kernel(
    const fp8_t* __restrict__ A, const fp8_t* __restrict__ B,
    const float* __restrict__ sa, const float* __restrict__ sb,
    const float* __restrict__ ra, const float* __restrict__ rb,
    const int* __restrict__ gt, float* __restrict__ out)
{
    __shared__ __align__(16) fp8_t As[BM * BKE];  // 16 KB
    __shared__ __align__(16) fp8_t Bs[BN * BKE];  // 16 KB

    const int tid  = threadIdx.x;
    const int wave = tid >> 6;
    const int lane = tid & 63;
    const int m0 = blockIdx.y * BM;
    const int n0 = blockIdx.x * BN;

    f32x4 acc[4][4] = {};

    const int fr = lane & 15;            // frag row (A) / frag col (B)
    const int q  = lane >> 4;            // quad
    const int wm = (wave >> 1) * 64;
    const int wn = (wave & 1) * 64;

    // staging: chunk c (16 B) -> row c>>3, slot c&7; LDS slot p of row holds
    // global chunk p ^ (row&7)   [XOR-8 swizzle]
    const int srow = lane >> 3;
    const int sp   = lane & 7;

    for (int k0 = 0; k0 < DIM; k0 += BKE) {
        __syncthreads();   // prev iter's LDS reads done
        #pragma unroll
        for (int j = 0; j < 4; ++j) {          // A: 1024 chunks, 256/wave
            const int c0  = wave * 256 + j * 64;            // wave-uniform
            const int row = (c0 >> 3) + srow;
            const int gcx = sp ^ (row & 7);
            const fp8_t* ga = A + (size_t)(m0 + row) * DIM + k0 + gcx * 16;
            __builtin_amdgcn_global_load_lds(
                (const __attribute__((address_space(1))) void*)ga,
                (__attribute__((address_space(3))) void*)(As + c0 * 16),
                16, 0, 0);
        }
        #pragma unroll
        for (int j = 0; j < 4; ++j) {          // B: 1024 chunks, 256/wave
            const int c0  = wave * 256 + j * 64;
            const int row = (c0 >> 3) + srow;
            const int gcx = sp ^ (row & 7);
            const fp8_t* gb = B + (size_t)(n0 + row) * DIM + k0 + gcx * 16;
            __builtin_amdgcn_global_load_lds(
                (const __attribute__((address_space(1))) void*)gb,
                (__attribute__((address_space(3))) void*)(Bs + c0 * 16),
                16, 0, 0);
        }
        __syncthreads();   // staging complete

        #pragma unroll
        for (int kk2 = 0; kk2 < 2; ++kk2) {    // each step: 2 K=32 windows
            const int c = kk2 * 4 + q;         // consecutive chunk per quad
            lng2 ap[4], bp[4];
            #pragma unroll
            for (int i = 0; i < 4; ++i) {
                const int ar = wm + i * 16 + fr;
                const int br = wn + i * 16 + fr;
                ap[i] = *(const lng2*)(As + ar * BKE + ((c ^ (ar & 7)) * 16));
                bp[i] = *(const lng2*)(Bs + br * BKE + ((c ^ (br & 7)) * 16));
            }
            #pragma unroll
            for (int mi = 0; mi < 4; ++mi)
                #pragma unroll
                for (int ni = 0; ni < 4; ++ni)
                    acc[mi][ni] = __builtin_amdgcn_mfma_f32_16x16x32_fp8_fp8(
                        ap[mi][0], bp[ni][0], acc[mi][ni], 0, 0, 0);
            #pragma unroll
            for (int mi = 0; mi < 4; ++mi)
                #pragma unroll
                for (int ni = 0; ni < 4; ++ni)
                    acc[mi][ni] = __builtin_amdgcn_mfma_f32_16x16x32_fp8_fp8(
                        ap[mi][1], bp[ni][1], acc[mi][ni], 0, 0, 0);
        }
    }

    // ---- fused epilogue: C/D col=lane&15, row=(lane>>4)*4+reg ----
    // Single traversal; per-element exact correction branch (never taken for
    // this data: min d2 ~ 1250 >> 4) — no dup loop, no spill trigger.
    // gt read directly: per (mi,rr) the thread loads 4 ints at col stride
    // 16; per wave these tile 256B-aligned segments, each byte read once.
    const int cq = lane & 15;
    const int rq = (lane >> 4) * 4;

    float cc[4];
    #pragma unroll
    for (int ni = 0; ni < 4; ++ni) {
        const int col = n0 + wn + ni * 16 + cq;
        cc[ni] = sb[col] - 2.0f * EPSV * rb[col];
    }

    float local = 0.0f;
    #pragma unroll
    for (int mi = 0; mi < 4; ++mi) {
        #pragma unroll
        for (int rr = 0; rr < 4; ++rr) {
            const int row = m0 + wm + mi * 16 + rq + rr;
            const float crr = sa[row] + 2.0f * EPSV * ra[row]
                            + (float)DIM * EPSV * EPSV;
            const int* gr = gt + (size_t)row * NROWS + n0 + wn + cq;
            int gvals[4];
            #pragma unroll
            for (int ni = 0; ni < 4; ++ni) gvals[ni] = gr[ni * 16];
            #pragma unroll
            for (int ni = 0; ni < 4; ++ni) {
                const float d2 = (crr + cc[ni]) - 2.0f * acc[mi][ni][rr];
                const float gf = (gvals[ni] != 0) ? 1.0f : 0.0f;
                float contrib = d2 - gf * d2;           // hinge==0 fast path
                if (__builtin_expect(d2 < 4.0f, 0)) {   // exact, never taken
                    const float d2c  = fmaxf(d2, 0.0f);
                    const float dist = sqrtf(d2c);
                    const float h    = fmaxf(MARGIN - dist, 0.0f);
                    contrib = (1.0f - gf) * d2c + gf * h * h;
                }
                local += contrib;
            }
        }
    }

    #pragma unroll
    for (int off = 32; off > 0; off >>= 1) local += __shfl_down(local, off);

    float* redp = (float*)As;   // reuse LDS for block reduction
    __syncthreads();
    if (lane == 0) redp[wave] = local;
    __syncthreads();
    if (tid == 0) {
        const float s = (redp[0] + redp[1]) + (redp[2] + redp[3]);
        atomicAdd(out, s * (1.0f / (4096.0f * 4096.0f)));
    }
}

// ---------------------------------------------------------------------------
extern "C" void kernel_launch(void* const* d_in, const int* in_sizes, int n_in,
                              void* d_out, int out_size, void* d_ws, size_t ws_size,
                              hipStream_t stream)
{
    const float* A  = (const float*)d_in[0];
    const float* B  = (const float*)d_in[1];
    const int*   gt = (const int*)d_in[2];
    float* out = (float*)d_out;

    char* ws = (char*)d_ws;
    const size_t NB8 = (size_t)NROWS * DIM;   // 3,145,728 B per fp8 matrix
    fp8_t* Af8 = (fp8_t*)(ws);
    fp8_t* Bf8 = (fp8_t*)(ws + NB8);
    float* sa = (float*)(ws + 2 * NB8);
    float* sb = (float*)(ws + 2 * NB8 + 16384);
    float* ra = (float*)(ws + 2 * NB8 + 32768);
    float* rb = (float*)(ws + 2 * NB8 + 49152);

    prologue_kernel<<<dim3(2048), 256, 0, stream>>>(
        A, B, Af8, Bf8, sa, sb, ra, rb, out);
    loss_kernel<<<dim3(NROWS / BN, NROWS / BM), 256, 0, stream>>>(
        Af8, Bf8, sa, sb, ra, rb, gt, out);
}